// Round 7
// baseline (750.813 us; speedup 1.0000x reference)
//
#include <hip/hip_runtime.h>
#include <math.h>

typedef _Float16 f16;
typedef _Float16 f16x2 __attribute__((ext_vector_type(2)));
typedef _Float16 f16x4 __attribute__((ext_vector_type(4)));
typedef _Float16 f16x8 __attribute__((ext_vector_type(8)));
typedef float    f32x4 __attribute__((ext_vector_type(4)));

#define PKRTZ(a, b) __builtin_bit_cast(f16x2, __builtin_amdgcn_cvt_pkrtz((a), (b)))

#define NN 8192
#define DD 64
#define KT 32
#define NQB 64
#define NWAVES 8
#define KPW (NN / NWAVES)      // 1024 keys per wave
#define NTILES (KPW / KT)      // 32

#define LOG2E 1.44269504088896f

// ---------------- kernel A: f32 -> f16 natural (Xn) + 32-key-tiled transpose (Xv) ----
// Xn: [b][n][d] f16.  Xv: [b][kt][d][k'] f16, kt = key-tile of 32, k' = key within tile.
#define LT_PITCH 66   // f16; stride = 33 dwords -> phase-2 reads walk banks +1 (conflict-free)
__global__ __launch_bounds__(256, 2)
void prep_f16(const float* __restrict__ X, f16* __restrict__ Xn, f16* __restrict__ Xv)
{
  __shared__ f16 Lt[64 * LT_PITCH];
  const int tid  = threadIdx.x;
  const int b    = blockIdx.x >> 7;
  const int kb64 = (blockIdx.x & 127) * 64;

  // phase 1: coalesced read, cvt, write Xn + stash in LDS
  {
    const int r = tid >> 2;            // key row 0..63
    const int c = (tid & 3) * 16;      // d col group
    const float* p = X + ((size_t)(b * NN + kb64 + r)) * DD + c;
    const float4 a0 = *(const float4*)(p);
    const float4 a1 = *(const float4*)(p + 4);
    const float4 a2 = *(const float4*)(p + 8);
    const float4 a3 = *(const float4*)(p + 12);
    f16x8 v0, v1;
    v0[0]=(f16)a0.x; v0[1]=(f16)a0.y; v0[2]=(f16)a0.z; v0[3]=(f16)a0.w;
    v0[4]=(f16)a1.x; v0[5]=(f16)a1.y; v0[6]=(f16)a1.z; v0[7]=(f16)a1.w;
    v1[0]=(f16)a2.x; v1[1]=(f16)a2.y; v1[2]=(f16)a2.z; v1[3]=(f16)a2.w;
    v1[4]=(f16)a3.x; v1[5]=(f16)a3.y; v1[6]=(f16)a3.z; v1[7]=(f16)a3.w;
    f16* dn = Xn + ((size_t)(b * NN + kb64 + r)) * DD + c;
    *(f16x8*)(dn)     = v0;
    *(f16x8*)(dn + 8) = v1;
    *(f16x8*)&Lt[r * LT_PITCH + c]     = v0;
    *(f16x8*)&Lt[r * LT_PITCH + c + 8] = v1;
  }
  __syncthreads();
  // phase 2: all 256 threads; each writes 16 keys of one d-row of one 32-key tile
  {
    const int h    = tid >> 7;          // which 32-key tile of the 64-key block
    const int rem  = tid & 127;
    const int d    = rem >> 1;
    const int half = rem & 1;           // which 16-key half within the tile
    union { f16 s[16]; f16x8 v[2]; } u;
    #pragma unroll
    for (int j = 0; j < 16; ++j)
      u.s[j] = Lt[(h * 32 + half * 16 + j) * LT_PITCH + d];
    const int kt = (kb64 >> 5) + h;
    f16* dst = Xv + (((size_t)(b * (NN / 32) + kt)) * DD + d) * 32 + half * 16;
    *(f16x8*)&dst[0] = u.v[0];
    *(f16x8*)&dst[8] = u.v[1];
  }
}

// ---------------- kernel B: attention + projection ----------------
#define P_PITCH 36                       // f16; rows 72 B, b64 ops 8B-aligned, <=2-way banks
#define P_BYTES (64 * P_PITCH * 2)       // 4608 per wave; 8 waves = 36864
#define HL_PITCH 68
#define WL_OFF  (64 * HL_PITCH * 4)      // 17408
#define LST_OFF (2 * 64 * HL_PITCH * 4)  // 34816
#define SMEM_B  (NWAVES * P_BYTES)       // 36864 (epilogue overlay fits: 35072+256)

struct Frag { f16x8 ka[2][2]; f16x8 vb[4]; };

__global__ __launch_bounds__(512, 4)
void gconv_attn(const float* __restrict__ X, const f16* __restrict__ Xn,
                const f16* __restrict__ Xv, const float* __restrict__ W,
                float* __restrict__ out)
{
  __shared__ __align__(16) unsigned char smem[SMEM_B];

  const int tid  = threadIdx.x;
  const int lane = tid & 63;
  const int wave = tid >> 6;
  const int q15  = lane & 15;
  const int quad = lane >> 4;

  const int batch = blockIdx.x >> 7;
  const int qbase = (blockIdx.x & 127) * NQB;
  const float* Xb = X + (size_t)batch * NN * DD;

  f16* Pw = (f16*)(smem + wave * P_BYTES);

  const f16* XnW = Xn + ((size_t)batch * NN + wave * KPW) * DD + q15 * DD + quad * 8;
  const f16* XvW = Xv + (((size_t)batch * (NN / 32) + wave * NTILES)) * DD * 32
                      + q15 * 32 + quad * 8;

  // ---- Q fragments (B-operand: n=q15 query, k=c*32+quad*8+j d), exp2 domain ----
  f16x8 qf[4][2];
  float m2[4], lrow[4];
  #pragma unroll
  for (int qt = 0; qt < 4; ++qt) {
    const float* qp = Xb + (size_t)(qbase + qt*16 + q15) * DD + quad*8;
    float nrm = 0.f;
    #pragma unroll
    for (int c = 0; c < 2; ++c) {
      const float4 a = *(const float4*)(qp + c*32);
      const float4 b = *(const float4*)(qp + c*32 + 4);
      float xs[8] = {a.x, a.y, a.z, a.w, b.x, b.y, b.z, b.w};
      f16x8 v;
      #pragma unroll
      for (int e = 0; e < 8; ++e) {
        const f16 ks = (f16)xs[e];
        const f16 qs = (f16)(xs[e] * LOG2E);
        nrm += (float)qs * (float)ks;
        v[e] = qs;
      }
      qf[qt][c] = v;
    }
    nrm += __shfl_xor(nrm, 16);
    nrm += __shfl_xor(nrm, 32);
    m2[qt] = nrm + 2.0f;
    lrow[qt] = 0.f;
  }

  f32x4 acc[4][4];
  #pragma unroll
  for (int a = 0; a < 4; ++a)
    #pragma unroll
    for (int b = 0; b < 4; ++b)
      acc[a][b] = (f32x4){0.f, 0.f, 0.f, 0.f};

  auto load_frag = [&](Frag& f, int t) {
    const f16* kn = XnW + (size_t)t * (KT * DD);
    #pragma unroll
    for (int g = 0; g < 2; ++g)
      #pragma unroll
      for (int c = 0; c < 2; ++c)
        f.ka[g][c] = *(const f16x8*)(kn + g * 16 * DD + c * 32);
    const f16* vn = XvW + (size_t)t * (DD * 32);
    #pragma unroll
    for (int mt = 0; mt < 4; ++mt)
      f.vb[mt] = *(const f16x8*)(vn + mt * 16 * 32);
  };

  auto process = [&](const Frag& f) {
    #pragma unroll
    for (int qt = 0; qt < 4; ++qt) {
      #pragma unroll
      for (int g = 0; g < 2; ++g) {
        f32x4 s = (f32x4){0.f, 0.f, 0.f, 0.f};
        s = __builtin_amdgcn_mfma_f32_16x16x32_f16(f.ka[g][0], qf[qt][0], s, 0, 0, 0);
        s = __builtin_amdgcn_mfma_f32_16x16x32_f16(f.ka[g][1], qf[qt][1], s, 0, 0, 0);
        const float p0 = __builtin_amdgcn_exp2f(s[0] - m2[qt]);
        const float p1 = __builtin_amdgcn_exp2f(s[1] - m2[qt]);
        const float p2 = __builtin_amdgcn_exp2f(s[2] - m2[qt]);
        const float p3 = __builtin_amdgcn_exp2f(s[3] - m2[qt]);
        lrow[qt] += (p0 + p1) + (p2 + p3);
        union { f16x4 v; f16x2 h[2]; } pu;
        pu.h[0] = PKRTZ(p0, p1);
        pu.h[1] = PKRTZ(p2, p3);
        *(f16x4*)&Pw[(qt*16 + q15)*P_PITCH + g*16 + quad*4] = pu.v;
      }
    }
    #pragma unroll
    for (int qt = 0; qt < 4; ++qt) {
      union { f16x8 v; f16x4 h[2]; } pu;
      pu.h[0] = *(const f16x4*)&Pw[(qt*16 + q15)*P_PITCH + quad*8];
      pu.h[1] = *(const f16x4*)&Pw[(qt*16 + q15)*P_PITCH + quad*8 + 4];
      #pragma unroll
      for (int mt = 0; mt < 4; ++mt)
        acc[qt][mt] = __builtin_amdgcn_mfma_f32_16x16x32_f16(f.vb[mt], pu.v, acc[qt][mt], 0, 0, 0);
    }
  };

  // ---- software-pipelined main loop (register double-buffer) ----
  Frag f0, f1;
  load_frag(f0, 0);
  for (int t = 0; t < NTILES; t += 2) {
    const int t1 = (t + 1 < NTILES) ? t + 1 : t;
    const int t2 = (t + 2 < NTILES) ? t + 2 : t1;
    load_frag(f1, t1);
    process(f0);
    load_frag(f0, t2);
    process(f1);
  }

  // ========= merge across 8 key-split waves (shared m2: plain sums) =========
  __syncthreads();
  float* Hl    = (float*)smem;
  float* Wl    = (float*)(smem + WL_OFF);
  float* Lstar = (float*)(smem + LST_OFF);

  for (int i = tid; i < 64*HL_PITCH; i += 512) Hl[i] = 0.f;
  for (int i = tid; i < 64*64; i += 512) Wl[(i >> 6)*HL_PITCH + (i & 63)] = W[i];
  if (tid < 64) Lstar[tid] = 0.f;
  __syncthreads();

  #pragma unroll
  for (int qt = 0; qt < 4; ++qt) {
    float lr = lrow[qt];
    lr += __shfl_xor(lr, 16);
    lr += __shfl_xor(lr, 32);
    if (quad == 0) atomicAdd(&Lstar[qt*16 + q15], lr);
    #pragma unroll
    for (int mt = 0; mt < 4; ++mt)
      #pragma unroll
      for (int rr = 0; rr < 4; ++rr)
        atomicAdd(&Hl[(mt*16 + quad*4 + rr)*HL_PITCH + qt*16 + q15], acc[qt][mt][rr]);
  }
  __syncthreads();

  // ========= projection: out = (H / l) . W =========
  {
    const int qq = tid >> 3;          // 64 queries, 8 threads each
    const int og = (tid & 7) * 8;     // 8 outputs per thread
    f32x4 o0 = (f32x4){0.f,0.f,0.f,0.f}, o1 = (f32x4){0.f,0.f,0.f,0.f};
    for (int d = 0; d < 64; ++d) {
      const float h = Hl[d*HL_PITCH + qq];
      const f32x4 w0 = *(const f32x4*)&Wl[d*HL_PITCH + og];
      const f32x4 w1 = *(const f32x4*)&Wl[d*HL_PITCH + og + 4];
      o0 += h * w0;
      o1 += h * w1;
    }
    const float inv = 1.0f / Lstar[qq];
    float* op = out + ((size_t)batch * NN + qbase + qq) * DD + og;
    *(f32x4*)(op)     = o0 * inv;
    *(f32x4*)(op + 4) = o1 * inv;
  }
}

extern "C" void kernel_launch(void* const* d_in, const int* in_sizes, int n_in,
                              void* d_out, int out_size, void* d_ws, size_t ws_size,
                              hipStream_t stream) {
  const float* X = (const float*)d_in[0];   // [4, 8192, 64] fp32
  const float* W = (const float*)d_in[1];   // [64, 64] fp32
  float* out = (float*)d_out;               // [4, 8192, 64] fp32

  f16* Xn = (f16*)d_ws;                                    // 4 MiB
  f16* Xv = (f16*)((char*)d_ws + (size_t)4 * NN * DD * 2); // 4 MiB
  prep_f16<<<dim3(512), dim3(256), 0, stream>>>(X, Xn, Xv);
  gconv_attn<<<dim3(512), dim3(512), 0, stream>>>(X, Xn, Xv, W, out);
}

// Round 8
// 355.622 us; speedup vs baseline: 2.1113x; 2.1113x over previous
//
#include <hip/hip_runtime.h>
#include <math.h>

typedef _Float16 f16;
typedef _Float16 f16x2 __attribute__((ext_vector_type(2)));
typedef _Float16 f16x4 __attribute__((ext_vector_type(4)));
typedef _Float16 f16x8 __attribute__((ext_vector_type(8)));
typedef float    f32x4 __attribute__((ext_vector_type(4)));

#define PKRTZ(a, b) __builtin_bit_cast(f16x2, __builtin_amdgcn_cvt_pkrtz((a), (b)))

#define NN 8192
#define DD 64
#define KT 32
#define NQB 32                 // queries per block (halved: acc fits 128-reg budget)
#define NWAVES 8
#define KPW (NN / NWAVES)      // 1024 keys per wave
#define NTILES (KPW / KT)      // 32

#define LOG2E 1.44269504088896f

// ---------------- kernel A: f32 -> f16 natural (Xn) + 32-key-tiled transpose (Xv) ----
#define LT_PITCH 66
__global__ __launch_bounds__(256, 2)
void prep_f16(const float* __restrict__ X, f16* __restrict__ Xn, f16* __restrict__ Xv)
{
  __shared__ f16 Lt[64 * LT_PITCH];
  const int tid  = threadIdx.x;
  const int b    = blockIdx.x >> 7;
  const int kb64 = (blockIdx.x & 127) * 64;

  {
    const int r = tid >> 2;
    const int c = (tid & 3) * 16;
    const float* p = X + ((size_t)(b * NN + kb64 + r)) * DD + c;
    const float4 a0 = *(const float4*)(p);
    const float4 a1 = *(const float4*)(p + 4);
    const float4 a2 = *(const float4*)(p + 8);
    const float4 a3 = *(const float4*)(p + 12);
    f16x8 v0, v1;
    v0[0]=(f16)a0.x; v0[1]=(f16)a0.y; v0[2]=(f16)a0.z; v0[3]=(f16)a0.w;
    v0[4]=(f16)a1.x; v0[5]=(f16)a1.y; v0[6]=(f16)a1.z; v0[7]=(f16)a1.w;
    v1[0]=(f16)a2.x; v1[1]=(f16)a2.y; v1[2]=(f16)a2.z; v1[3]=(f16)a2.w;
    v1[4]=(f16)a3.x; v1[5]=(f16)a3.y; v1[6]=(f16)a3.z; v1[7]=(f16)a3.w;
    f16* dn = Xn + ((size_t)(b * NN + kb64 + r)) * DD + c;
    *(f16x8*)(dn)     = v0;
    *(f16x8*)(dn + 8) = v1;
    *(f16x8*)&Lt[r * LT_PITCH + c]     = v0;
    *(f16x8*)&Lt[r * LT_PITCH + c + 8] = v1;
  }
  __syncthreads();
  {
    const int h    = tid >> 7;
    const int rem  = tid & 127;
    const int d    = rem >> 1;
    const int half = rem & 1;
    union { f16 s[16]; f16x8 v[2]; } u;
    #pragma unroll
    for (int j = 0; j < 16; ++j)
      u.s[j] = Lt[(h * 32 + half * 16 + j) * LT_PITCH + d];
    const int kt = (kb64 >> 5) + h;
    f16* dst = Xv + (((size_t)(b * (NN / 32) + kt)) * DD + d) * 32 + half * 16;
    *(f16x8*)&dst[0] = u.v[0];
    *(f16x8*)&dst[8] = u.v[1];
  }
}

// ---------------- kernel B: attention + projection (32 q / block, 8-way key split) ----
#define P_PITCH 36                        // f16; <=2-way banks, b64-aligned rows
#define P_BYTES (NQB * P_PITCH * 2)       // 2304 per wave; 8 waves = 18432
// epilogue overlay:
#define HL_PITCH 36                       // Hl [d=64][q=32] f32
#define HL_BYTES (64 * HL_PITCH * 4)      // 9216
#define WL_PITCH 68
#define WL_OFF   HL_BYTES                 // Wl [d=64][o=64] f32 pitch 68 -> 17408
#define LST_OFF  (WL_OFF + 64 * WL_PITCH * 4)   // 26624
#define SMEM_B   (LST_OFF + NQB * 4)      // 26752 (>= 8*P_BYTES=18432)

__global__ __launch_bounds__(512, 4)
void gconv_attn(const float* __restrict__ X, const f16* __restrict__ Xn,
                const f16* __restrict__ Xv, const float* __restrict__ W,
                float* __restrict__ out)
{
  __shared__ __align__(16) unsigned char smem[SMEM_B];

  const int tid  = threadIdx.x;
  const int lane = tid & 63;
  const int wave = tid >> 6;
  const int q15  = lane & 15;
  const int quad = lane >> 4;

  // XCD-aware mapping: XCD = blockIdx%8 (heuristic) -> batch fixed per XCD pair;
  // each XCD's L2 working set = one batch's Xn+Xv (2 MB < 4 MB L2).
  const int batch = (blockIdx.x & 7) >> 1;
  const int qidx  = (blockIdx.x >> 3) * 2 + (blockIdx.x & 1);   // 0..255 within batch
  const int qbase = qidx * NQB;
  const float* Xb = X + (size_t)batch * NN * DD;

  f16* Pw = (f16*)(smem + wave * P_BYTES);

  const f16* XnW = Xn + ((size_t)batch * NN + wave * KPW) * DD + q15 * DD + quad * 8;
  const f16* XvW = Xv + (((size_t)batch * (NN / 32) + wave * NTILES)) * DD * 32
                      + q15 * 32 + quad * 8;

  // ---- Q fragments (B-operand), exp2 domain; static max m2 ----
  f16x8 qf[2][2];
  float m2[2], lrow[2];
  #pragma unroll
  for (int qt = 0; qt < 2; ++qt) {
    const float* qp = Xb + (size_t)(qbase + qt*16 + q15) * DD + quad*8;
    float nrm = 0.f;
    #pragma unroll
    for (int c = 0; c < 2; ++c) {
      const float4 a = *(const float4*)(qp + c*32);
      const float4 b = *(const float4*)(qp + c*32 + 4);
      float xs[8] = {a.x, a.y, a.z, a.w, b.x, b.y, b.z, b.w};
      f16x8 v;
      #pragma unroll
      for (int e = 0; e < 8; ++e) {
        const f16 ks = (f16)xs[e];
        const f16 qs = (f16)(xs[e] * LOG2E);
        nrm += (float)qs * (float)ks;
        v[e] = qs;
      }
      qf[qt][c] = v;
    }
    nrm += __shfl_xor(nrm, 16);
    nrm += __shfl_xor(nrm, 32);
    m2[qt] = nrm + 2.0f;
    lrow[qt] = 0.f;
  }

  f32x4 acc[2][4];
  #pragma unroll
  for (int a = 0; a < 2; ++a)
    #pragma unroll
    for (int b = 0; b < 4; ++b)
      acc[a][b] = (f32x4){0.f, 0.f, 0.f, 0.f};

  // ka double-buffered (K rows, A-operand); vb loaded per-tile (acts as prefetch
  // across the QK/softmax phase).
  f16x8 kaA[2][2], kaB[2][2];

  auto load_ka = [&](f16x8 (&ka)[2][2], int t) {
    const f16* kn = XnW + (size_t)t * (KT * DD);
    #pragma unroll
    for (int g = 0; g < 2; ++g)
      #pragma unroll
      for (int c = 0; c < 2; ++c)
        ka[g][c] = *(const f16x8*)(kn + g * 16 * DD + c * 32);
  };

  auto process = [&](const f16x8 (&ka)[2][2], int t) {
    // issue V loads first (latency covered by QK+softmax below)
    const f16* vn = XvW + (size_t)t * (DD * 32);
    f16x8 vb[4];
    #pragma unroll
    for (int mt = 0; mt < 4; ++mt)
      vb[mt] = *(const f16x8*)(vn + mt * 16 * 32);

    #pragma unroll
    for (int qt = 0; qt < 2; ++qt) {
      #pragma unroll
      for (int g = 0; g < 2; ++g) {
        f32x4 s = (f32x4){0.f, 0.f, 0.f, 0.f};
        s = __builtin_amdgcn_mfma_f32_16x16x32_f16(ka[g][0], qf[qt][0], s, 0, 0, 0);
        s = __builtin_amdgcn_mfma_f32_16x16x32_f16(ka[g][1], qf[qt][1], s, 0, 0, 0);
        const float p0 = __builtin_amdgcn_exp2f(s[0] - m2[qt]);
        const float p1 = __builtin_amdgcn_exp2f(s[1] - m2[qt]);
        const float p2 = __builtin_amdgcn_exp2f(s[2] - m2[qt]);
        const float p3 = __builtin_amdgcn_exp2f(s[3] - m2[qt]);
        lrow[qt] += (p0 + p1) + (p2 + p3);
        union { f16x4 v; f16x2 h[2]; } pu;
        pu.h[0] = PKRTZ(p0, p1);
        pu.h[1] = PKRTZ(p2, p3);
        *(f16x4*)&Pw[(qt*16 + q15)*P_PITCH + g*16 + quad*4] = pu.v;
      }
    }
    #pragma unroll
    for (int qt = 0; qt < 2; ++qt) {
      union { f16x8 v; f16x4 h[2]; } pu;
      pu.h[0] = *(const f16x4*)&Pw[(qt*16 + q15)*P_PITCH + quad*8];
      pu.h[1] = *(const f16x4*)&Pw[(qt*16 + q15)*P_PITCH + quad*8 + 4];
      #pragma unroll
      for (int mt = 0; mt < 4; ++mt)
        acc[qt][mt] = __builtin_amdgcn_mfma_f32_16x16x32_f16(vb[mt], pu.v, acc[qt][mt], 0, 0, 0);
    }
  };

  load_ka(kaA, 0);
  for (int t = 0; t < NTILES; t += 2) {
    load_ka(kaB, t + 1 < NTILES ? t + 1 : t);
    process(kaA, t);
    load_ka(kaA, t + 2 < NTILES ? t + 2 : t);
    process(kaB, t + 1 < NTILES ? t + 1 : t);
  }

  // ========= merge across 8 key-split waves (shared m2: plain sums) =========
  __syncthreads();
  float* Hl    = (float*)smem;
  float* Wl    = (float*)(smem + WL_OFF);
  float* Lstar = (float*)(smem + LST_OFF);

  for (int i = tid; i < 64*HL_PITCH; i += 512) Hl[i] = 0.f;
  for (int i = tid; i < 64*64; i += 512) Wl[(i >> 6)*WL_PITCH + (i & 63)] = W[i];
  if (tid < NQB) Lstar[tid] = 0.f;
  __syncthreads();

  #pragma unroll
  for (int qt = 0; qt < 2; ++qt) {
    float lr = lrow[qt];
    lr += __shfl_xor(lr, 16);
    lr += __shfl_xor(lr, 32);
    if (quad == 0) atomicAdd(&Lstar[qt*16 + q15], lr);
    #pragma unroll
    for (int mt = 0; mt < 4; ++mt)
      #pragma unroll
      for (int rr = 0; rr < 4; ++rr)
        atomicAdd(&Hl[(mt*16 + quad*4 + rr)*HL_PITCH + qt*16 + q15], acc[qt][mt][rr]);
  }
  __syncthreads();

  // ========= projection: out = (H / l) . W =========
  {
    const int qq = tid >> 4;          // 32 queries, 16 threads each
    const int og = (tid & 15) * 4;    // 4 outputs per thread
    f32x4 o = (f32x4){0.f,0.f,0.f,0.f};
    for (int d = 0; d < 64; ++d) {
      const float h = Hl[d*HL_PITCH + qq];
      o += h * *(const f32x4*)&Wl[d*WL_PITCH + og];
    }
    const float inv = 1.0f / Lstar[qq];
    float* op = out + ((size_t)batch * NN + qbase + qq) * DD + og;
    *(f32x4*)op = o * inv;
  }
}

extern "C" void kernel_launch(void* const* d_in, const int* in_sizes, int n_in,
                              void* d_out, int out_size, void* d_ws, size_t ws_size,
                              hipStream_t stream) {
  const float* X = (const float*)d_in[0];   // [4, 8192, 64] fp32
  const float* W = (const float*)d_in[1];   // [64, 64] fp32
  float* out = (float*)d_out;               // [4, 8192, 64] fp32

  f16* Xn = (f16*)d_ws;                                    // 4 MiB
  f16* Xv = (f16*)((char*)d_ws + (size_t)4 * NN * DD * 2); // 4 MiB
  prep_f16<<<dim3(512), dim3(256), 0, stream>>>(X, Xn, Xv);
  gconv_attn<<<dim3(1024), dim3(512), 0, stream>>>(X, Xn, Xv, W, out);
}

// Round 9
// 335.347 us; speedup vs baseline: 2.2389x; 1.0605x over previous
//
#include <hip/hip_runtime.h>
#include <math.h>

typedef _Float16 f16;
typedef _Float16 f16x2 __attribute__((ext_vector_type(2)));
typedef _Float16 f16x4 __attribute__((ext_vector_type(4)));
typedef _Float16 f16x8 __attribute__((ext_vector_type(8)));
typedef float    f32x4 __attribute__((ext_vector_type(4)));

#define PKRTZ(a, b) __builtin_bit_cast(f16x2, __builtin_amdgcn_cvt_pkrtz((a), (b)))

#define NN 8192
#define DD 64
#define KT 32
#define NQB 32                 // queries per block
#define NWAVES 8
#define KPW (NN / NWAVES)      // 1024 keys per wave
#define NTILES (KPW / KT)      // 32

#define LOG2E 1.44269504088896f

// ---------------- kernel A: f32 -> f16 natural (Xn) + 32-key-tiled transpose (Xv) ----
#define LT_PITCH 66
__global__ __launch_bounds__(256, 2)
void prep_f16(const float* __restrict__ X, f16* __restrict__ Xn, f16* __restrict__ Xv)
{
  __shared__ f16 Lt[64 * LT_PITCH];
  const int tid  = threadIdx.x;
  const int b    = blockIdx.x >> 7;
  const int kb64 = (blockIdx.x & 127) * 64;

  {
    const int r = tid >> 2;
    const int c = (tid & 3) * 16;
    const float* p = X + ((size_t)(b * NN + kb64 + r)) * DD + c;
    const float4 a0 = *(const float4*)(p);
    const float4 a1 = *(const float4*)(p + 4);
    const float4 a2 = *(const float4*)(p + 8);
    const float4 a3 = *(const float4*)(p + 12);
    f16x8 v0, v1;
    v0[0]=(f16)a0.x; v0[1]=(f16)a0.y; v0[2]=(f16)a0.z; v0[3]=(f16)a0.w;
    v0[4]=(f16)a1.x; v0[5]=(f16)a1.y; v0[6]=(f16)a1.z; v0[7]=(f16)a1.w;
    v1[0]=(f16)a2.x; v1[1]=(f16)a2.y; v1[2]=(f16)a2.z; v1[3]=(f16)a2.w;
    v1[4]=(f16)a3.x; v1[5]=(f16)a3.y; v1[6]=(f16)a3.z; v1[7]=(f16)a3.w;
    f16* dn = Xn + ((size_t)(b * NN + kb64 + r)) * DD + c;
    *(f16x8*)(dn)     = v0;
    *(f16x8*)(dn + 8) = v1;
    *(f16x8*)&Lt[r * LT_PITCH + c]     = v0;
    *(f16x8*)&Lt[r * LT_PITCH + c + 8] = v1;
  }
  __syncthreads();
  {
    const int h    = tid >> 7;
    const int rem  = tid & 127;
    const int d    = rem >> 1;
    const int half = rem & 1;
    union { f16 s[16]; f16x8 v[2]; } u;
    #pragma unroll
    for (int j = 0; j < 16; ++j)
      u.s[j] = Lt[(h * 32 + half * 16 + j) * LT_PITCH + d];
    const int kt = (kb64 >> 5) + h;
    f16* dst = Xv + (((size_t)(b * (NN / 32) + kt)) * DD + d) * 32 + half * 16;
    *(f16x8*)&dst[0] = u.v[0];
    *(f16x8*)&dst[8] = u.v[1];
  }
}

// ---------------- kernel B: attention + projection (32 q / block, 8-way key split) ----
#define P_PITCH 36                        // f16; <=2-way banks, b64-aligned rows
#define P_BYTES (NQB * P_PITCH * 2)       // 2304 per wave; 8 waves = 18432
// epilogue overlay:
#define HL_PITCH 36                       // Hl [d=64][q=32] f32
#define HL_BYTES (64 * HL_PITCH * 4)      // 9216
#define WL_PITCH 68
#define WL_OFF   HL_BYTES                 // Wl [d=64][o=64] f32 pitch 68
#define LST_OFF  (WL_OFF + 64 * WL_PITCH * 4)   // 26624
#define SMEM_B   (LST_OFF + NQB * 4)      // 26752

// NOTE: 2nd launch_bounds arg behaves as MIN BLOCKS PER CU (CUDA semantics) on
// this toolchain — (512,4) produced a 64-VGPR cap (R4/R7/R8 spill disasters).
// (512,2) = 16 waves/CU, 128-VGPR cap: fits this kernel's ~100-reg state.
__global__ __launch_bounds__(512, 2)
void gconv_attn(const float* __restrict__ X, const f16* __restrict__ Xn,
                const f16* __restrict__ Xv, const float* __restrict__ W,
                float* __restrict__ out)
{
  __shared__ __align__(16) unsigned char smem[SMEM_B];

  const int tid  = threadIdx.x;
  const int lane = tid & 63;
  const int wave = tid >> 6;
  const int q15  = lane & 15;
  const int quad = lane >> 4;

  const int batch = (blockIdx.x & 7) >> 1;
  const int qidx  = (blockIdx.x >> 3) * 2 + (blockIdx.x & 1);
  const int qbase = qidx * NQB;
  const float* Xb = X + (size_t)batch * NN * DD;

  f16* Pw = (f16*)(smem + wave * P_BYTES);

  const f16* XnW = Xn + ((size_t)batch * NN + wave * KPW) * DD + q15 * DD + quad * 8;
  const f16* XvW = Xv + (((size_t)batch * (NN / 32) + wave * NTILES)) * DD * 32
                      + q15 * 32 + quad * 8;

  // ---- Q fragments (B-operand), exp2 domain; static max m2 ----
  f16x8 qf[2][2];
  float m2[2], lrow[2];
  #pragma unroll
  for (int qt = 0; qt < 2; ++qt) {
    const float* qp = Xb + (size_t)(qbase + qt*16 + q15) * DD + quad*8;
    float nrm = 0.f;
    #pragma unroll
    for (int c = 0; c < 2; ++c) {
      const float4 a = *(const float4*)(qp + c*32);
      const float4 b = *(const float4*)(qp + c*32 + 4);
      float xs[8] = {a.x, a.y, a.z, a.w, b.x, b.y, b.z, b.w};
      f16x8 v;
      #pragma unroll
      for (int e = 0; e < 8; ++e) {
        const f16 ks = (f16)xs[e];
        const f16 qs = (f16)(xs[e] * LOG2E);
        nrm += (float)qs * (float)ks;
        v[e] = qs;
      }
      qf[qt][c] = v;
    }
    nrm += __shfl_xor(nrm, 16);
    nrm += __shfl_xor(nrm, 32);
    m2[qt] = nrm + 2.0f;
    lrow[qt] = 0.f;
  }

  f32x4 acc[2][4];
  #pragma unroll
  for (int a = 0; a < 2; ++a)
    #pragma unroll
    for (int b = 0; b < 4; ++b)
      acc[a][b] = (f32x4){0.f, 0.f, 0.f, 0.f};

  f16x8 kaA[2][2], kaB[2][2];

  auto load_ka = [&](f16x8 (&ka)[2][2], int t) {
    const f16* kn = XnW + (size_t)t * (KT * DD);
    #pragma unroll
    for (int g = 0; g < 2; ++g)
      #pragma unroll
      for (int c = 0; c < 2; ++c)
        ka[g][c] = *(const f16x8*)(kn + g * 16 * DD + c * 32);
  };

  auto process = [&](const f16x8 (&ka)[2][2], int t) {
    const f16* vn = XvW + (size_t)t * (DD * 32);
    f16x8 vb[4];
    #pragma unroll
    for (int mt = 0; mt < 4; ++mt)
      vb[mt] = *(const f16x8*)(vn + mt * 16 * 32);

    #pragma unroll
    for (int qt = 0; qt < 2; ++qt) {
      #pragma unroll
      for (int g = 0; g < 2; ++g) {
        f32x4 s = (f32x4){0.f, 0.f, 0.f, 0.f};
        s = __builtin_amdgcn_mfma_f32_16x16x32_f16(ka[g][0], qf[qt][0], s, 0, 0, 0);
        s = __builtin_amdgcn_mfma_f32_16x16x32_f16(ka[g][1], qf[qt][1], s, 0, 0, 0);
        const float p0 = __builtin_amdgcn_exp2f(s[0] - m2[qt]);
        const float p1 = __builtin_amdgcn_exp2f(s[1] - m2[qt]);
        const float p2 = __builtin_amdgcn_exp2f(s[2] - m2[qt]);
        const float p3 = __builtin_amdgcn_exp2f(s[3] - m2[qt]);
        lrow[qt] += (p0 + p1) + (p2 + p3);
        union { f16x4 v; f16x2 h[2]; } pu;
        pu.h[0] = PKRTZ(p0, p1);
        pu.h[1] = PKRTZ(p2, p3);
        *(f16x4*)&Pw[(qt*16 + q15)*P_PITCH + g*16 + quad*4] = pu.v;
      }
    }
    #pragma unroll
    for (int qt = 0; qt < 2; ++qt) {
      union { f16x8 v; f16x4 h[2]; } pu;
      pu.h[0] = *(const f16x4*)&Pw[(qt*16 + q15)*P_PITCH + quad*8];
      pu.h[1] = *(const f16x4*)&Pw[(qt*16 + q15)*P_PITCH + quad*8 + 4];
      #pragma unroll
      for (int mt = 0; mt < 4; ++mt)
        acc[qt][mt] = __builtin_amdgcn_mfma_f32_16x16x32_f16(vb[mt], pu.v, acc[qt][mt], 0, 0, 0);
    }
  };

  load_ka(kaA, 0);
  for (int t = 0; t < NTILES; t += 2) {
    load_ka(kaB, t + 1 < NTILES ? t + 1 : t);
    process(kaA, t);
    load_ka(kaA, t + 2 < NTILES ? t + 2 : t);
    process(kaB, t + 1 < NTILES ? t + 1 : t);
  }

  // ========= merge across 8 key-split waves (shared m2: plain sums) =========
  __syncthreads();
  float* Hl    = (float*)smem;
  float* Wl    = (float*)(smem + WL_OFF);
  float* Lstar = (float*)(smem + LST_OFF);

  for (int i = tid; i < 64*HL_PITCH; i += 512) Hl[i] = 0.f;
  for (int i = tid; i < 64*64; i += 512) Wl[(i >> 6)*WL_PITCH + (i & 63)] = W[i];
  if (tid < NQB) Lstar[tid] = 0.f;
  __syncthreads();

  #pragma unroll
  for (int qt = 0; qt < 2; ++qt) {
    float lr = lrow[qt];
    lr += __shfl_xor(lr, 16);
    lr += __shfl_xor(lr, 32);
    if (quad == 0) atomicAdd(&Lstar[qt*16 + q15], lr);
    #pragma unroll
    for (int mt = 0; mt < 4; ++mt)
      #pragma unroll
      for (int rr = 0; rr < 4; ++rr)
        atomicAdd(&Hl[(mt*16 + quad*4 + rr)*HL_PITCH + qt*16 + q15], acc[qt][mt][rr]);
  }
  __syncthreads();

  // ========= projection: out = (H / l) . W =========
  {
    const int qq = tid >> 4;          // 32 queries, 16 threads each
    const int og = (tid & 15) * 4;    // 4 outputs per thread
    f32x4 o = (f32x4){0.f,0.f,0.f,0.f};
    for (int d = 0; d < 64; ++d) {
      const float h = Hl[d*HL_PITCH + qq];
      o += h * *(const f32x4*)&Wl[d*WL_PITCH + og];
    }
    const float inv = 1.0f / Lstar[qq];
    float* op = out + ((size_t)batch * NN + qbase + qq) * DD + og;
    *(f32x4*)op = o * inv;
  }
}

extern "C" void kernel_launch(void* const* d_in, const int* in_sizes, int n_in,
                              void* d_out, int out_size, void* d_ws, size_t ws_size,
                              hipStream_t stream) {
  const float* X = (const float*)d_in[0];   // [4, 8192, 64] fp32
  const float* W = (const float*)d_in[1];   // [64, 64] fp32
  float* out = (float*)d_out;               // [4, 8192, 64] fp32

  f16* Xn = (f16*)d_ws;                                    // 4 MiB
  f16* Xv = (f16*)((char*)d_ws + (size_t)4 * NN * DD * 2); // 4 MiB
  prep_f16<<<dim3(512), dim3(256), 0, stream>>>(X, Xn, Xv);
  gconv_attn<<<dim3(1024), dim3(512), 0, stream>>>(X, Xn, Xv, W, out);
}